// Round 1
// baseline (487.557 us; speedup 1.0000x reference)
//
#include <hip/hip_runtime.h>

// instant-NGP hash-grid encoder, 12 levels, F=2, N = 1<<20 points.
// Levels 0-4 dense (R^3 <= 2^19), levels 5-11 hashed with table size 2^19.

#define N_LEVELS 12

__global__ __launch_bounds__(256) void grid_encode_kernel(
    const float* __restrict__ x,
    const float* __restrict__ params,
    float* __restrict__ out,
    int N)
{
    int n = blockIdx.x * blockDim.x + threadIdx.x;
    if (n >= N) return;

    const float px = x[3 * n + 0];
    const float py = x[3 * n + 1];
    const float pz = x[3 * n + 2];

    // compile-time level tables
    constexpr int   RES[N_LEVELS]     = {16, 23, 32, 46, 64, 92, 128, 184, 256, 368, 512, 736};
    constexpr unsigned OFF[N_LEVELS]  = {0u, 4096u, 16264u, 49032u, 146368u, 408512u,
                                         932800u, 1457088u, 1981376u, 2505664u, 3029952u, 3554240u};
    // dense iff R^3 <= level table size; true for levels 0..4
    constexpr unsigned HASH_MASK = 524287u;           // 2^19 - 1 (all hashed levels are exactly 2^19)
    constexpr unsigned P1 = 2654435761u;
    constexpr unsigned P2 = 805459861u;

    float res[2 * N_LEVELS];

#pragma unroll
    for (int l = 0; l < N_LEVELS; ++l) {
        const int   r  = RES[l];
        const float rs = (float)(r - 1);

        float fx = px * rs, fy = py * rs, fz = pz * rs;
        float f0x = fminf(fmaxf(floorf(fx), 0.0f), (float)(r - 2));
        float f0y = fminf(fmaxf(floorf(fy), 0.0f), (float)(r - 2));
        float f0z = fminf(fmaxf(floorf(fz), 0.0f), (float)(r - 2));
        float wx1 = fx - f0x, wy1 = fy - f0y, wz1 = fz - f0z;
        float wx[2] = {1.0f - wx1, wx1};
        float wy[2] = {1.0f - wy1, wy1};
        float wz[2] = {1.0f - wz1, wz1};

        unsigned ix = (unsigned)f0x;
        unsigned iy = (unsigned)f0y;
        unsigned iz = (unsigned)f0z;

        const float2* __restrict__ tab = (const float2*)params + OFF[l];

        float s0 = 0.0f, s1 = 0.0f;

        const bool dense = ((long long)r * r * r) <= (long long)524288;  // constexpr-folded per level
        if (dense) {
            const unsigned rr = (unsigned)(r * r);
            const unsigned base = ix + iy * (unsigned)r + iz * rr;
#pragma unroll
            for (int c = 0; c < 8; ++c) {
                const unsigned dx = c & 1, dy = (c >> 1) & 1, dz = (c >> 2) & 1;
                const unsigned idx = base + dx + dy * (unsigned)r + dz * rr;
                float2 f = tab[idx];
                float wc = (wx[dx] * wy[dy]) * wz[dz];
                s0 = fmaf(wc, f.x, s0);
                s1 = fmaf(wc, f.y, s1);
            }
        } else {
            const unsigned hx[2] = {ix, ix + 1u};
            const unsigned hy[2] = {iy * P1, (iy + 1u) * P1};
            const unsigned hz[2] = {iz * P2, (iz + 1u) * P2};
#pragma unroll
            for (int c = 0; c < 8; ++c) {
                const unsigned dx = c & 1, dy = (c >> 1) & 1, dz = (c >> 2) & 1;
                const unsigned idx = (hx[dx] ^ hy[dy] ^ hz[dz]) & HASH_MASK;
                float2 f = tab[idx];
                float wc = (wx[dx] * wy[dy]) * wz[dz];
                s0 = fmaf(wc, f.x, s0);
                s1 = fmaf(wc, f.y, s1);
            }
        }

        res[2 * l + 0] = s0;
        res[2 * l + 1] = s1;
    }

    // 24 floats per point, 16B-aligned (24*4 = 96 = 6*16) -> 6 float4 stores
    float4* __restrict__ o4 = (float4*)(out + (size_t)n * 24);
#pragma unroll
    for (int k = 0; k < 6; ++k) {
        float4 v;
        v.x = res[4 * k + 0];
        v.y = res[4 * k + 1];
        v.z = res[4 * k + 2];
        v.w = res[4 * k + 3];
        o4[k] = v;
    }
}

extern "C" void kernel_launch(void* const* d_in, const int* in_sizes, int n_in,
                              void* d_out, int out_size, void* d_ws, size_t ws_size,
                              hipStream_t stream) {
    const float* x      = (const float*)d_in[0];
    const float* params = (const float*)d_in[1];
    float* out          = (float*)d_out;

    const int N = in_sizes[0] / 3;  // 1<<20
    const int block = 256;
    const int grid = (N + block - 1) / block;
    grid_encode_kernel<<<grid, block, 0, stream>>>(x, params, out, N);
}

// Round 2
// 327.625 us; speedup vs baseline: 1.4882x; 1.4882x over previous
//
#include <hip/hip_runtime.h>

// instant-NGP hash-grid encoder, 12 levels, F=2, N = 1<<20 points.
// Levels 0-4 dense (R^3 <= 2^19), levels 5-11 hashed (table = 2^19 entries = 4 MB).
//
// Strategy: per-XCD L2 is 4 MB; the fused kernel thrashes it with 28 MB of
// hashed tables. Split into one pass per hashed level (gridDim.y = level,
// x-major dispatch => ~1 table live per XCD L2 at a time), staging results in
// d_ws [7][N] float2 (coalesced), then a merge kernel does the 5 dense levels
// (3.3 MB of tables, L2-resident) + coalesced gather of ws + float4 stores.

#define N_LEVELS 12
#define N_HASHED 7

__device__ __forceinline__ void trilinear_setup(float p, int r, float* w, unsigned* i0)
{
    float f  = p * (float)(r - 1);
    float f0 = fminf(fmaxf(floorf(f), 0.0f), (float)(r - 2));
    float w1 = f - f0;
    w[0] = 1.0f - w1;
    w[1] = w1;
    *i0 = (unsigned)f0;
}

// ---------------- pass 1: hashed levels (5..11), one level per blockIdx.y ----
__global__ __launch_bounds__(256) void hashed_levels_kernel(
    const float* __restrict__ x,
    const float* __restrict__ params,
    float2* __restrict__ ws,   // [N_HASHED][N]
    int N)
{
    constexpr int      HRES[N_HASHED] = {92, 128, 184, 256, 368, 512, 736};
    constexpr unsigned HOFF[N_HASHED] = {408512u, 932800u, 1457088u, 1981376u,
                                         2505664u, 3029952u, 3554240u};
    constexpr unsigned HASH_MASK = 524287u;   // 2^19 - 1
    constexpr unsigned P1 = 2654435761u;
    constexpr unsigned P2 = 805459861u;

    const int n = blockIdx.x * blockDim.x + threadIdx.x;
    if (n >= N) return;
    const int li = blockIdx.y;          // 0..6 -> level 5+li

    const float px = x[3 * n + 0];
    const float py = x[3 * n + 1];
    const float pz = x[3 * n + 2];

    const int r = HRES[li];
    float wx[2], wy[2], wz[2];
    unsigned ix, iy, iz;
    trilinear_setup(px, r, wx, &ix);
    trilinear_setup(py, r, wy, &iy);
    trilinear_setup(pz, r, wz, &iz);

    const float2* __restrict__ tab = (const float2*)params + HOFF[li];

    const unsigned hx[2] = {ix, ix + 1u};
    const unsigned hy[2] = {iy * P1, (iy + 1u) * P1};
    const unsigned hz[2] = {iz * P2, (iz + 1u) * P2};

    float s0 = 0.0f, s1 = 0.0f;
#pragma unroll
    for (int c = 0; c < 8; ++c) {
        const unsigned dx = c & 1, dy = (c >> 1) & 1, dz = (c >> 2) & 1;
        const unsigned idx = (hx[dx] ^ hy[dy] ^ hz[dz]) & HASH_MASK;
        float2 f = tab[idx];
        float wc = (wx[dx] * wy[dy]) * wz[dz];
        s0 = fmaf(wc, f.x, s0);
        s1 = fmaf(wc, f.y, s1);
    }

    ws[(size_t)li * N + n] = make_float2(s0, s1);
}

// ---------------- pass 2: dense levels (0..4) + merge + coalesced store -----
__global__ __launch_bounds__(256) void dense_merge_kernel(
    const float* __restrict__ x,
    const float* __restrict__ params,
    const float2* __restrict__ ws,   // [N_HASHED][N]
    float* __restrict__ out,
    int N)
{
    constexpr int      DRES[5] = {16, 23, 32, 46, 64};
    constexpr unsigned DOFF[5] = {0u, 4096u, 16264u, 49032u, 146368u};

    const int n = blockIdx.x * blockDim.x + threadIdx.x;
    if (n >= N) return;

    const float px = x[3 * n + 0];
    const float py = x[3 * n + 1];
    const float pz = x[3 * n + 2];

    float res[2 * N_LEVELS];

#pragma unroll
    for (int l = 0; l < 5; ++l) {
        const int r = DRES[l];
        float wx[2], wy[2], wz[2];
        unsigned ix, iy, iz;
        trilinear_setup(px, r, wx, &ix);
        trilinear_setup(py, r, wy, &iy);
        trilinear_setup(pz, r, wz, &iz);

        const float2* __restrict__ tab = (const float2*)params + DOFF[l];
        const unsigned rr = (unsigned)(r * r);
        const unsigned base = ix + iy * (unsigned)r + iz * rr;

        float s0 = 0.0f, s1 = 0.0f;
#pragma unroll
        for (int c = 0; c < 8; ++c) {
            const unsigned dx = c & 1, dy = (c >> 1) & 1, dz = (c >> 2) & 1;
            const unsigned idx = base + dx + dy * (unsigned)r + dz * rr;
            float2 f = tab[idx];
            float wc = (wx[dx] * wy[dy]) * wz[dz];
            s0 = fmaf(wc, f.x, s0);
            s1 = fmaf(wc, f.y, s1);
        }
        res[2 * l + 0] = s0;
        res[2 * l + 1] = s1;
    }

#pragma unroll
    for (int li = 0; li < N_HASHED; ++li) {
        float2 f = ws[(size_t)li * N + n];    // coalesced: stride-8B in n
        res[2 * (5 + li) + 0] = f.x;
        res[2 * (5 + li) + 1] = f.y;
    }

    float4* __restrict__ o4 = (float4*)(out + (size_t)n * 24);
#pragma unroll
    for (int k = 0; k < 6; ++k) {
        float4 v;
        v.x = res[4 * k + 0];
        v.y = res[4 * k + 1];
        v.z = res[4 * k + 2];
        v.w = res[4 * k + 3];
        o4[k] = v;
    }
}

// ---------------- fallback: fused single kernel (round-1 version) -----------
__global__ __launch_bounds__(256) void grid_encode_fused_kernel(
    const float* __restrict__ x,
    const float* __restrict__ params,
    float* __restrict__ out,
    int N)
{
    int n = blockIdx.x * blockDim.x + threadIdx.x;
    if (n >= N) return;

    const float px = x[3 * n + 0];
    const float py = x[3 * n + 1];
    const float pz = x[3 * n + 2];

    constexpr int   RES[N_LEVELS]    = {16, 23, 32, 46, 64, 92, 128, 184, 256, 368, 512, 736};
    constexpr unsigned OFF[N_LEVELS] = {0u, 4096u, 16264u, 49032u, 146368u, 408512u,
                                        932800u, 1457088u, 1981376u, 2505664u, 3029952u, 3554240u};
    constexpr unsigned HASH_MASK = 524287u;
    constexpr unsigned P1 = 2654435761u;
    constexpr unsigned P2 = 805459861u;

    float res[2 * N_LEVELS];

#pragma unroll
    for (int l = 0; l < N_LEVELS; ++l) {
        const int r = RES[l];
        float wx[2], wy[2], wz[2];
        unsigned ix, iy, iz;
        trilinear_setup(px, r, wx, &ix);
        trilinear_setup(py, r, wy, &iy);
        trilinear_setup(pz, r, wz, &iz);

        const float2* __restrict__ tab = (const float2*)params + OFF[l];
        float s0 = 0.0f, s1 = 0.0f;

        const bool dense = ((long long)r * r * r) <= (long long)524288;
        if (dense) {
            const unsigned rr = (unsigned)(r * r);
            const unsigned base = ix + iy * (unsigned)r + iz * rr;
#pragma unroll
            for (int c = 0; c < 8; ++c) {
                const unsigned dx = c & 1, dy = (c >> 1) & 1, dz = (c >> 2) & 1;
                const unsigned idx = base + dx + dy * (unsigned)r + dz * rr;
                float2 f = tab[idx];
                float wc = (wx[dx] * wy[dy]) * wz[dz];
                s0 = fmaf(wc, f.x, s0);
                s1 = fmaf(wc, f.y, s1);
            }
        } else {
            const unsigned hx[2] = {ix, ix + 1u};
            const unsigned hy[2] = {iy * P1, (iy + 1u) * P1};
            const unsigned hz[2] = {iz * P2, (iz + 1u) * P2};
#pragma unroll
            for (int c = 0; c < 8; ++c) {
                const unsigned dx = c & 1, dy = (c >> 1) & 1, dz = (c >> 2) & 1;
                const unsigned idx = (hx[dx] ^ hy[dy] ^ hz[dz]) & HASH_MASK;
                float2 f = tab[idx];
                float wc = (wx[dx] * wy[dy]) * wz[dz];
                s0 = fmaf(wc, f.x, s0);
                s1 = fmaf(wc, f.y, s1);
            }
        }
        res[2 * l + 0] = s0;
        res[2 * l + 1] = s1;
    }

    float4* __restrict__ o4 = (float4*)(out + (size_t)n * 24);
#pragma unroll
    for (int k = 0; k < 6; ++k) {
        float4 v;
        v.x = res[4 * k + 0];
        v.y = res[4 * k + 1];
        v.z = res[4 * k + 2];
        v.w = res[4 * k + 3];
        o4[k] = v;
    }
}

extern "C" void kernel_launch(void* const* d_in, const int* in_sizes, int n_in,
                              void* d_out, int out_size, void* d_ws, size_t ws_size,
                              hipStream_t stream) {
    const float* x      = (const float*)d_in[0];
    const float* params = (const float*)d_in[1];
    float* out          = (float*)d_out;

    const int N = in_sizes[0] / 3;  // 1<<20
    const int block = 256;
    const int gx = (N + block - 1) / block;

    const size_t ws_needed = (size_t)N_HASHED * (size_t)N * sizeof(float2);  // 56 MB

    if (ws_size >= ws_needed) {
        float2* ws = (float2*)d_ws;
        dim3 grid1(gx, N_HASHED, 1);
        hashed_levels_kernel<<<grid1, block, 0, stream>>>(x, params, ws, N);
        dense_merge_kernel<<<gx, block, 0, stream>>>(x, params, ws, out, N);
    } else {
        grid_encode_fused_kernel<<<gx, block, 0, stream>>>(x, params, out, N);
    }
}